// Round 4
// baseline (1159.513 us; speedup 1.0000x reference)
//
#include <hip/hip_runtime.h>
#include <stdint.h>

#define NN 20000
#define NE 32000
#define BN_EPS 1e-5f

typedef __attribute__((ext_vector_type(8))) __bf16 bf16x8;
typedef __attribute__((ext_vector_type(4))) float f32x4;
typedef unsigned short u16;
typedef uint32_t u32;

__device__ __forceinline__ u16 f2bf(float f) {
    u32 u = __float_as_uint(f);
    u += 0x7FFFu + ((u >> 16) & 1u);
    return (u16)(u >> 16);
}
__device__ __forceinline__ float bf2f(u16 u) {
    return __uint_as_float(((u32)u) << 16);
}

__device__ __forceinline__ void gload_lds16(const void* g, void* l) {
    __builtin_amdgcn_global_load_lds(
        (const __attribute__((address_space(1))) void*)g,
        (__attribute__((address_space(3))) void*)(uintptr_t)l,
        16, 0, 0);
}

// ============ shared 8-phase machinery (T2+T3+T4+T5), 256x256, BK=64 ============
#define LDSRD(base, r, cb) (*(const bf16x8*)((const char*)(base) + (r)*128 + (cb)))

#define DS_A(apb, qm) do { \
  _Pragma("unroll") for (int m4_ = 0; m4_ < 4; ++m4_) { \
    int r_ = (qm)*128 + m4_*32 + wr16 + lrow; \
    aR[m4_][0] = LDSRD(apb, r_, cb0); \
    aR[m4_][1] = LDSRD(apb, r_, cb1); \
  } } while (0)

#define DS_B(bpb, qn) do { \
  _Pragma("unroll") for (int n2_ = 0; n2_ < 2; ++n2_) { \
    int n_ = (qn)*2 + n2_; \
    int r_ = n_*64 + wc16 + lrow; \
    bR[n_][0] = LDSRD(bpb, r_, cb0); \
    bR[n_][1] = LDSRD(bpb, r_, cb1); \
  } } while (0)

#define MM(qm, qn) do { \
  _Pragma("unroll") for (int m4_ = 0; m4_ < 4; ++m4_) \
  _Pragma("unroll") for (int n2_ = 0; n2_ < 2; ++n2_) { \
    int mi_ = (qm)*4 + m4_, ni_ = (qn)*2 + n2_; \
    acc[mi_][ni_] = __builtin_amdgcn_mfma_f32_16x16x32_bf16(aR[m4_][0], bR[ni_][0], acc[mi_][ni_], 0, 0, 0); \
    acc[mi_][ni_] = __builtin_amdgcn_mfma_f32_16x16x32_bf16(aR[m4_][1], bR[ni_][1], acc[mi_][ni_], 0, 0, 0); \
  } } while (0)

#define PHASE_TOP() do { __builtin_amdgcn_s_barrier(); \
  asm volatile("s_waitcnt lgkmcnt(0)" ::: "memory"); \
  __builtin_amdgcn_s_setprio(1); } while (0)
#define PHASE_END() do { __builtin_amdgcn_s_setprio(0); \
  __builtin_amdgcn_s_barrier(); } while (0)
#define PHASE_END_VM() do { __builtin_amdgcn_s_setprio(0); \
  asm volatile("s_waitcnt vmcnt(6)" ::: "memory"); \
  __builtin_amdgcn_s_barrier(); } while (0)

// K-loop body (identical schedule in both kernels); SA/SB are kernel-local macros
#define KLOOP_BODY(nit_) do { \
  for (int it = 0; it < (nit_); ++it) { \
    const int t1 = 2 * it + 1, t2 = 2 * it + 2, t3 = 2 * it + 3; \
    DS_A(&As[0][0][0], 0); DS_B(&Bs[0][0][0], 0); \
    SA(1, 1, t1); \
    PHASE_TOP(); MM(0, 0); PHASE_END(); \
    DS_B(&Bs[0][0][0], 1); \
    SA(0, 0, t2); \
    PHASE_TOP(); MM(0, 1); PHASE_END(); \
    DS_A(&As[0][0][0], 1); \
    SB(0, 0, t2); \
    PHASE_TOP(); MM(1, 1); PHASE_END(); \
    SB(0, 1, t2); \
    __builtin_amdgcn_s_barrier(); \
    __builtin_amdgcn_s_setprio(1); \
    MM(1, 0); \
    PHASE_END_VM(); \
    DS_A(&As[1][0][0], 0); DS_B(&Bs[1][0][0], 0); \
    SA(0, 1, t2); \
    PHASE_TOP(); MM(0, 0); PHASE_END(); \
    DS_B(&Bs[1][0][0], 1); \
    SA(1, 0, t3); \
    PHASE_TOP(); MM(0, 1); PHASE_END(); \
    DS_A(&As[1][0][0], 1); \
    SB(1, 0, t3); \
    PHASE_TOP(); MM(1, 1); PHASE_END(); \
    SB(1, 1, t3); \
    __builtin_amdgcn_s_barrier(); \
    __builtin_amdgcn_s_setprio(1); \
    MM(1, 0); \
    PHASE_END_VM(); \
  } } while (0)

// ================== GEMM1 fused (role-split L/R, A-row indirection) ==================
// role L: y1l[c][0:1680] = xbf[clist[c]] @ W1l^T  (c < nsrc, compacted src rows)
// role R: y1r[i][0:1680] = xbf[i]        @ W1r^T  (all NN rows)
// w1T = [3360][5120] bf16 rows = output cols; rows 0..1679 = W1l, 1680..3359 = W1r.
__global__ __launch_bounds__(512, 2) void gemm1f(
    const u16* __restrict__ xbf, const u16* __restrict__ w1T,
    u16* __restrict__ y1l, u16* __restrict__ y1r,
    const int* __restrict__ clist, const int* __restrict__ nsrcp)
{
    __shared__ __align__(16) u16 As[2][256][64];
    __shared__ __align__(16) u16 Bs[2][256][64];
    const int K = 5120, lda = 5120;
    const int Km64 = K - 64;

    const int nsrc = nsrcp[0];
    const int nmt_l = (nsrc + 255) >> 8;
    const int nl = nmt_l * 7;

    // bijective XCD swizzle over fixed nwg = 1106
    int bid = blockIdx.x;
    const int nwg = 1106;
    int q8 = nwg >> 3, r8 = nwg & 7;
    int xcd = bid & 7, lid = bid >> 3;
    int wgid = (xcd < r8 ? xcd * (q8 + 1) : r8 * (q8 + 1) + (xcd - r8) * q8) + lid;

    int roleL = (wgid < nl);
    int local, nmt;
    if (roleL) { local = wgid; nmt = nmt_l; }
    else {
        local = wgid - nl;
        if (local >= 553) return;      // block-uniform early exit, before any barrier
        nmt = 79;
    }
    // grouped raster GROUP_M=8, ntn=7
    int g = local / 56;
    int first = g << 3;
    int gsz = nmt - first; gsz = gsz < 8 ? gsz : 8;
    int rem = local - g * 56;
    int mt = first + rem % gsz;
    int nt = rem / gsz;

    const int m0 = mt << 8, n0 = nt << 8;
    const int tid = threadIdx.x;
    const int wid = tid >> 6, ln = tid & 63;
    const int wr = wid >> 2, wc = wid & 3;
    const int lrow = ln & 15, khi = ln >> 4;
    const int wr16 = wr << 4, wc16 = wc << 4;
    const int cb0 = (khi << 4) ^ ((lrow & 7) << 4);
    const int cb1 = cb0 ^ 64;
    const int row0 = tid >> 3;
    const int kel = ((tid & 7) ^ (row0 & 7)) << 3;
    const int dstoff = (tid & 448) << 4;

    // precomputed per-thread global row bases (i = ha*2 + {+0,+64})
    const u16* Bp = w1T + (roleL ? (size_t)0 : (size_t)1680 * 5120);
    const u16* aB[4];
    const u16* bB[4];
#pragma unroll
    for (int i = 0; i < 4; ++i) {
        int r = m0 + ((i >> 1) << 7) + ((i & 1) << 6) + row0;
        int ga;
        if (roleL) { int idx = r < nsrc ? r : nsrc - 1; ga = clist[idx]; }
        else       { ga = r < NN ? r : NN - 1; }
        aB[i] = xbf + (size_t)ga * lda + kel;
        int rb = n0 + ((i >> 1) << 7) + ((i & 1) << 6) + row0;
        rb = rb < 1680 ? rb : 1679;
        bB[i] = Bp + (size_t)rb * lda + kel;
    }

#define SA(b, ha, t) do { int ks_ = (t) * 64; if (ks_ > Km64) ks_ = Km64; \
  char* d_ = (char*)&As[b][(ha)*128][0] + dstoff; \
  gload_lds16(aB[(ha)*2] + ks_, d_); \
  gload_lds16(aB[(ha)*2 + 1] + ks_, d_ + 8192); } while (0)
#define SB(b, hb, t) do { int ks_ = (t) * 64; if (ks_ > Km64) ks_ = Km64; \
  char* d_ = (char*)&Bs[b][(hb)*128][0] + dstoff; \
  gload_lds16(bB[(hb)*2] + ks_, d_); \
  gload_lds16(bB[(hb)*2 + 1] + ks_, d_ + 8192); } while (0)

    f32x4 acc[8][4];
#pragma unroll
    for (int m = 0; m < 8; ++m)
#pragma unroll
        for (int n = 0; n < 4; ++n)
#pragma unroll
            for (int j = 0; j < 4; ++j) acc[m][n][j] = 0.f;
    bf16x8 aR[4][2], bR[4][2];

    SA(0, 0, 0); SB(0, 0, 0); SB(0, 1, 0); SA(0, 1, 0);
    SA(1, 0, 1); SB(1, 0, 1); SB(1, 1, 1);
    asm volatile("s_waitcnt vmcnt(6)" ::: "memory");
    __builtin_amdgcn_s_barrier();

    KLOOP_BODY(40);

#undef SA
#undef SB

    const int Meff = roleL ? nsrc : NN;
    u16* C = roleL ? y1l : y1r;
#pragma unroll
    for (int m = 0; m < 8; ++m) {
        int gr0 = m0 + m * 32 + wr16 + (khi << 2);
#pragma unroll
        for (int n = 0; n < 4; ++n) {
            int gc = n0 + n * 64 + wc16 + lrow;
            if (gc >= 1680) continue;
#pragma unroll
            for (int j = 0; j < 4; ++j) {
                int gr = gr0 + j;
                if (gr >= Meff) continue;
                C[(size_t)gr * 1680 + gc] = f2bf(acc[m][n][j]);
            }
        }
    }
}

// ================== generic 256x256 8-phase GEMM (GEMM2) ==================
__global__ __launch_bounds__(512, 2) void gemm256(
    const u16* __restrict__ A, const u16* __restrict__ B, u16* __restrict__ C,
    int M, int N, int K, int lda, int ldb, int ldc)
{
    __shared__ __align__(16) u16 As[2][256][64];
    __shared__ __align__(16) u16 Bs[2][256][64];

    const int nmt = (M + 255) >> 8;
    const int ntn = (N + 255) >> 8;
    const int nwg = nmt * ntn;

    int bid = blockIdx.x;
    int q8 = nwg >> 3, r8 = nwg & 7;
    int xcd = bid & 7, lid = bid >> 3;
    int wgid = (xcd < r8 ? xcd * (q8 + 1) : r8 * (q8 + 1) + (xcd - r8) * q8) + lid;
    int per = ntn << 3;
    int g = wgid / per;
    int first = g << 3;
    int gsz = nmt - first; gsz = gsz < 8 ? gsz : 8;
    int rem = wgid - g * per;
    int mt = first + rem % gsz;
    int nt = rem / gsz;

    const int m0 = mt << 8, n0 = nt << 8;
    const int tid = threadIdx.x;
    const int wid = tid >> 6, ln = tid & 63;
    const int wr = wid >> 2, wc = wid & 3;
    const int lrow = ln & 15, khi = ln >> 4;
    const int wr16 = wr << 4, wc16 = wc << 4;
    const int cb0 = (khi << 4) ^ ((lrow & 7) << 4);
    const int cb1 = cb0 ^ 64;
    const int row0 = tid >> 3;
    const int kel = ((tid & 7) ^ (row0 & 7)) << 3;
    const int dstoff = (tid & 448) << 4;
    const int Km64 = K - 64;

#define SA(b, ha, t) do { int ks_ = (t) * 64; if (ks_ > Km64) ks_ = Km64; \
  int ra_ = m0 + (ha)*128 + row0;      ra_ = ra_ < M ? ra_ : M - 1; \
  int rb_ = m0 + (ha)*128 + row0 + 64; rb_ = rb_ < M ? rb_ : M - 1; \
  char* d_ = (char*)&As[b][(ha)*128][0] + dstoff; \
  gload_lds16(A + (size_t)ra_ * lda + ks_ + kel, d_); \
  gload_lds16(A + (size_t)rb_ * lda + ks_ + kel, d_ + 8192); } while (0)
#define SB(b, hb, t) do { int ks_ = (t) * 64; if (ks_ > Km64) ks_ = Km64; \
  int ra_ = n0 + (hb)*128 + row0;      ra_ = ra_ < N ? ra_ : N - 1; \
  int rb_ = n0 + (hb)*128 + row0 + 64; rb_ = rb_ < N ? rb_ : N - 1; \
  char* d_ = (char*)&Bs[b][(hb)*128][0] + dstoff; \
  gload_lds16(B + (size_t)ra_ * ldb + ks_ + kel, d_); \
  gload_lds16(B + (size_t)rb_ * ldb + ks_ + kel, d_ + 8192); } while (0)

    f32x4 acc[8][4];
#pragma unroll
    for (int m = 0; m < 8; ++m)
#pragma unroll
        for (int n = 0; n < 4; ++n)
#pragma unroll
            for (int j = 0; j < 4; ++j) acc[m][n][j] = 0.f;
    bf16x8 aR[4][2], bR[4][2];

    SA(0, 0, 0); SB(0, 0, 0); SB(0, 1, 0); SA(0, 1, 0);
    SA(1, 0, 1); SB(1, 0, 1); SB(1, 1, 1);
    asm volatile("s_waitcnt vmcnt(6)" ::: "memory");
    __builtin_amdgcn_s_barrier();

    const int nit = K >> 7;
    KLOOP_BODY(nit);

#undef SA
#undef SB

#pragma unroll
    for (int m = 0; m < 8; ++m) {
        int gr0 = m0 + m * 32 + wr16 + (khi << 2);
#pragma unroll
        for (int n = 0; n < 4; ++n) {
            int gc = n0 + n * 64 + wc16 + lrow;
            if (gc >= N) continue;
#pragma unroll
            for (int j = 0; j < 4; ++j) {
                int gr = gr0 + j;
                if (gr >= M) continue;
                C[(size_t)gr * ldc + gc] = f2bf(acc[m][n][j]);
            }
        }
    }
}

// ================== 128x128 GEMM (small layers) ==================
template <int EPI>
__global__ __launch_bounds__(256, 2) void gemm_bt(
    const u16* __restrict__ A, const u16* __restrict__ B, u16* __restrict__ C,
    const float* __restrict__ bias, int M, int N, int K, int lda, int ldb, int ldc)
{
    __shared__ __align__(16) u16 As[128][64];
    __shared__ __align__(16) u16 Bs[128][64];

    const int nmt = (M + 127) >> 7;
    const int ntn = (N + 127) >> 7;
    int bid = blockIdx.x;
    int per_grp = 16 * ntn;
    int g = bid / per_grp;
    int first = g * 16;
    int gsz = min(16, nmt - first);
    int rem = bid - g * per_grp;
    int mt = first + rem % gsz;
    int nt = rem / gsz;

    const int m0 = mt << 7, n0 = nt << 7;
    const int tid = threadIdx.x;
    const int wv = tid >> 6, ln = tid & 63;
    const int wr = wv >> 1, wc = wv & 1;

    f32x4 acc[4][4];
#pragma unroll
    for (int m = 0; m < 4; ++m)
#pragma unroll
        for (int n = 0; n < 4; ++n)
#pragma unroll
            for (int j = 0; j < 4; ++j) acc[m][n][j] = 0.f;

    const int lrow = ln & 15;
    const int koff = (ln >> 4) << 3;

    for (int k0 = 0; k0 < K; k0 += 64) {
#pragma unroll
        for (int r = 0; r < 4; ++r) {
            int c = r * 256 + wv * 64 + ln;
            int row = c >> 3;
            int kc = (c & 7) << 3;
            int ga = m0 + row; ga = ga < M ? ga : M - 1;
            gload_lds16(A + (size_t)ga * lda + (k0 + kc),
                        (char*)&As[0][0] + (size_t)(r * 256 + wv * 64) * 16);
            int gb = n0 + row; gb = gb < N ? gb : N - 1;
            gload_lds16(B + (size_t)gb * ldb + (k0 + kc),
                        (char*)&Bs[0][0] + (size_t)(r * 256 + wv * 64) * 16);
        }
        __syncthreads();
#pragma unroll
        for (int kk = 0; kk < 2; ++kk) {
            bf16x8 af[4], bfr[4];
            const int krd = (kk << 5) + koff;
#pragma unroll
            for (int m = 0; m < 4; ++m)
                af[m] = *(const bf16x8*)&As[(wr << 6) + (m << 4) + lrow][krd];
#pragma unroll
            for (int n = 0; n < 4; ++n)
                bfr[n] = *(const bf16x8*)&Bs[(wc << 6) + (n << 4) + lrow][krd];
#pragma unroll
            for (int m = 0; m < 4; ++m)
#pragma unroll
                for (int n = 0; n < 4; ++n)
                    acc[m][n] = __builtin_amdgcn_mfma_f32_16x16x32_bf16(
                        af[m], bfr[n], acc[m][n], 0, 0, 0);
        }
        __syncthreads();
    }

    const int colb = ln & 15;
    const int rowb = (ln >> 4) << 2;
#pragma unroll
    for (int m = 0; m < 4; ++m) {
        int gr0 = m0 + (wr << 6) + (m << 4) + rowb;
#pragma unroll
        for (int n = 0; n < 4; ++n) {
            int gc = n0 + (wc << 6) + (n << 4) + colb;
            if (gc >= N) continue;
            float bv = (EPI == 1) ? bias[gc] : 0.f;
#pragma unroll
            for (int j = 0; j < 4; ++j) {
                int gr = gr0 + j;
                if (gr >= M) continue;
                float v = acc[m][n][j];
                if (EPI == 1) { v += bv; v = v > 0.f ? v : 0.f; }
                C[(size_t)gr * ldc + gc] = f2bf(v);
            }
        }
    }
}

// ---------------- fp32 -> bf16 convert (grid-stride)
__global__ void cvt_bf16(const float* __restrict__ in, u16* __restrict__ out, int n4)
{
    for (int i = blockIdx.x * 256 + threadIdx.x; i < n4; i += gridDim.x * 256) {
        float4 v = ((const float4*)in)[i];
        ushort4 o;
        o.x = f2bf(v.x); o.y = f2bf(v.y); o.z = f2bf(v.z); o.w = f2bf(v.w);
        ((ushort4*)out)[i] = o;
    }
}

// ---------------- weight transpose+convert: out[n][k](bf16,ld=Kpad) = src[k][n](f32)
__global__ void wtrans(const float* __restrict__ s0, const float* __restrict__ s1,
                       u16* __restrict__ out, int Kin, int Kpad, int N, int nsplit)
{
    __shared__ float t[32][33];
    int k0 = blockIdx.x << 5, n0 = blockIdx.y << 5;
    int tx = threadIdx.x, ty = threadIdx.y;
#pragma unroll
    for (int i = 0; i < 4; ++i) {
        int k = k0 + ty + (i << 3);
        int n = n0 + tx;
        float v = 0.f;
        if (k < Kin && n < N)
            v = (n < nsplit) ? s0[(size_t)k * nsplit + n]
                             : s1[(size_t)k * (N - nsplit) + (n - nsplit)];
        t[ty + (i << 3)][tx] = v;
    }
    __syncthreads();
#pragma unroll
    for (int i = 0; i < 4; ++i) {
        int n = n0 + ty + (i << 3);
        int k = k0 + tx;
        if (n < N && k < Kpad)
            out[(size_t)n * Kpad + k] = f2bf(t[tx][ty + (i << 3)]);
    }
}

// ================== CSR build + src compaction ==================
__global__ void deg_mark_k(const int* __restrict__ src, const int* __restrict__ dst,
                           int* __restrict__ deg, int* __restrict__ cmark, int ne)
{
    int e = blockIdx.x * 256 + threadIdx.x;
    if (e < ne) {
        atomicAdd(&deg[dst[e]], 1);
        cmark[src[e]] = 1;
    }
}

// single block: prefix-scan deg -> off/cur, prefix-scan cmark -> cidx (in place) + clist
__global__ __launch_bounds__(256) void scan2_k(
    const int* __restrict__ deg, int* __restrict__ off, int* __restrict__ cur,
    int* __restrict__ cmark, int* __restrict__ clist, int* __restrict__ nsrcp)
{
    __shared__ int part[256];
    int t = threadIdx.x;
    int st = t * 79;
    // scan 1: deg
    int s = 0;
    for (int j = 0; j < 79; ++j) { int i = st + j; if (i < NN) s += deg[i]; }
    part[t] = s;
    __syncthreads();
    for (int d = 1; d < 256; d <<= 1) {
        int v = (t >= d) ? part[t - d] : 0;
        __syncthreads(); part[t] += v; __syncthreads();
    }
    int run = part[t] - s;
    for (int j = 0; j < 79; ++j) {
        int i = st + j;
        if (i < NN) { off[i] = run; cur[i] = run; run += deg[i]; }
    }
    if (t == 255) off[NN] = NE;
    __syncthreads();
    // scan 2: cmark -> cidx (in place), emit clist
    int s2 = 0;
    for (int j = 0; j < 79; ++j) { int i = st + j; if (i < NN) s2 += cmark[i]; }
    part[t] = s2;
    __syncthreads();
    for (int d = 1; d < 256; d <<= 1) {
        int v = (t >= d) ? part[t - d] : 0;
        __syncthreads(); part[t] += v; __syncthreads();
    }
    int run2 = part[t] - s2;
    for (int j = 0; j < 79; ++j) {
        int i = st + j;
        if (i < NN) {
            int m = cmark[i];
            if (m) clist[run2] = i;
            cmark[i] = run2;       // cmark becomes cidx
            run2 += m;
        }
    }
    if (t == 255) nsrcp[0] = part[255];
}

__global__ void fill_k(const int* __restrict__ src, const int* __restrict__ dst,
                       int* __restrict__ cur, const int* __restrict__ cidx,
                       int* __restrict__ esrc, int ne)
{
    int e = blockIdx.x * 256 + threadIdx.x;
    if (e < ne) {
        int p = atomicAdd(&cur[dst[e]], 1);
        esrc[p] = cidx[src[e]];     // compact id
    }
}

// ================== fused gather-mean + epilogue, layer 1 ==================
__device__ __forceinline__ void bn_emit(
    int b, int c, float sx, float sy, float sz, float sw, float inv,
    const u16* __restrict__ y1r, const float* __restrict__ b1,
    const float* __restrict__ gam, const float* __restrict__ bet,
    const float* __restrict__ mn, const float* __restrict__ vr, u16* __restrict__ h)
{
    int col = c << 2;
    ushort4 yr = *(const ushort4*)&y1r[(size_t)b * 1680 + col];
    float4 bb = *(const float4*)&b1[col];
    float4 g4 = *(const float4*)&gam[col];
    float4 be = *(const float4*)&bet[col];
    float4 m4 = *(const float4*)&mn[col];
    float4 v4 = *(const float4*)&vr[col];
    float t0 = fmaxf(sx * inv + bb.x + bf2f(yr.x), 0.f);
    float t1 = fmaxf(sy * inv + bb.y + bf2f(yr.y), 0.f);
    float t2 = fmaxf(sz * inv + bb.z + bf2f(yr.z), 0.f);
    float t3 = fmaxf(sw * inv + bb.w + bf2f(yr.w), 0.f);
    t0 = (t0 - m4.x) * rsqrtf(v4.x + BN_EPS) * g4.x + be.x;
    t1 = (t1 - m4.y) * rsqrtf(v4.y + BN_EPS) * g4.y + be.y;
    t2 = (t2 - m4.z) * rsqrtf(v4.z + BN_EPS) * g4.z + be.z;
    t3 = (t3 - m4.w) * rsqrtf(v4.w + BN_EPS) * g4.w + be.w;
    ushort4 o;
    o.x = f2bf(t0); o.y = f2bf(t1); o.z = f2bf(t2); o.w = f2bf(t3);
    *(ushort4*)&h[(size_t)b * 1792 + col] = o;
}

__global__ __launch_bounds__(256) void agg_bn_k(
    const u16* __restrict__ y1l, const u16* __restrict__ y1r,
    const int* __restrict__ off, const int* __restrict__ esrc,
    const float* __restrict__ b1, const float* __restrict__ gam, const float* __restrict__ bet,
    const float* __restrict__ mn, const float* __restrict__ vr, u16* __restrict__ h)
{
    int b = blockIdx.x, t = threadIdx.x;
    int o0 = off[b], o1 = off[b + 1];
    int deg = o1 - o0;
    const int c0 = t, c1 = t + 256;   // ushort4 chunks; 420 data chunks, 448 total (pad)
    float s0x = 0.f, s0y = 0.f, s0z = 0.f, s0w = 0.f;
    float s1x = 0.f, s1y = 0.f, s1z = 0.f, s1w = 0.f;
    for (int j = o0; j < o1; ++j) {
        int s = esrc[j];            // compact id into y1l
        const u16* row = y1l + (size_t)s * 1680;
        ushort4 v = *(const ushort4*)&row[c0 << 2];
        s0x += bf2f(v.x); s0y += bf2f(v.y); s0z += bf2f(v.z); s0w += bf2f(v.w);
        if (t < 164) {
            ushort4 w = *(const ushort4*)&row[c1 << 2];
            s1x += bf2f(w.x); s1y += bf2f(w.y); s1z += bf2f(w.z); s1w += bf2f(w.w);
        }
    }
    float inv = 1.f / (deg > 1 ? (float)deg : 1.f);
    bn_emit(b, c0, s0x, s0y, s0z, s0w, inv, y1r, b1, gam, bet, mn, vr, h);
    if (t < 164) {
        bn_emit(b, c1, s1x, s1y, s1z, s1w, inv, y1r, b1, gam, bet, mn, vr, h);
    } else if (t < 192) {
        ushort4 z; z.x = 0; z.y = 0; z.z = 0; z.w = 0;
        *(ushort4*)&h[(size_t)b * 1792 + (c1 << 2)] = z;   // pad chunks 420..447
    }
}

// ================== fused gather-mean + epilogue, layer 2 ==================
__global__ __launch_bounds__(192) void agg_h2_k(
    const u16* __restrict__ y2, const int* __restrict__ off, const int* __restrict__ esrc,
    const int* __restrict__ clist, const int* __restrict__ nsrcp,
    const float* __restrict__ b2, u16* __restrict__ h2)
{
    int b = blockIdx.x, t = threadIdx.x;
    if (t >= 160) return;
    int o0 = off[b], o1 = off[b + 1];
    int deg = o1 - o0;
    float sx = 0.f, sy = 0.f, sz = 0.f, sw = 0.f;
    for (int j = o0; j < o1; ++j) {
        int s = clist[esrc[j]];     // original node id
        ushort4 v = *(const ushort4*)&y2[(size_t)s * 1280 + (t << 2)];
        sx += bf2f(v.x); sy += bf2f(v.y); sz += bf2f(v.z); sw += bf2f(v.w);
    }
    float inv = 1.f / (deg > 1 ? (float)deg : 1.f);
    int col = t << 2;
    ushort4 yr = *(const ushort4*)&y2[(size_t)b * 1280 + 640 + col];
    float4 bb = *(const float4*)&b2[col];
    ushort4 o;
    o.x = f2bf(fmaxf(sx * inv + bb.x + bf2f(yr.x), 0.f));
    o.y = f2bf(fmaxf(sy * inv + bb.y + bf2f(yr.y), 0.f));
    o.z = f2bf(fmaxf(sz * inv + bb.z + bf2f(yr.z), 0.f));
    o.w = f2bf(fmaxf(sw * inv + bb.w + bf2f(yr.w), 0.f));
    *(ushort4*)&h2[(size_t)b * 640 + col] = o;
}

// ---------------- final lin3
__global__ void lin3_k(const u16* __restrict__ o2, const float* __restrict__ W,
                       const float* __restrict__ b, float* __restrict__ out)
{
    __shared__ float ws[320];
    for (int j = threadIdx.x; j < 320; j += 256) ws[j] = W[j];
    __syncthreads();
    int i = blockIdx.x * 256 + threadIdx.x;
    if (i >= NN) return;
    float a0 = b[0], a1 = b[1];
    const u16* row = o2 + (size_t)i * 160;
#pragma unroll
    for (int k8 = 0; k8 < 20; ++k8) {
        ushort4 v0 = *(const ushort4*)&row[k8 * 8];
        ushort4 v1 = *(const ushort4*)&row[k8 * 8 + 4];
        int kb = k8 * 8;
        float f;
        f = bf2f(v0.x); a0 += f * ws[(kb + 0) * 2]; a1 += f * ws[(kb + 0) * 2 + 1];
        f = bf2f(v0.y); a0 += f * ws[(kb + 1) * 2]; a1 += f * ws[(kb + 1) * 2 + 1];
        f = bf2f(v0.z); a0 += f * ws[(kb + 2) * 2]; a1 += f * ws[(kb + 2) * 2 + 1];
        f = bf2f(v0.w); a0 += f * ws[(kb + 3) * 2]; a1 += f * ws[(kb + 3) * 2 + 1];
        f = bf2f(v1.x); a0 += f * ws[(kb + 4) * 2]; a1 += f * ws[(kb + 4) * 2 + 1];
        f = bf2f(v1.y); a0 += f * ws[(kb + 5) * 2]; a1 += f * ws[(kb + 5) * 2 + 1];
        f = bf2f(v1.z); a0 += f * ws[(kb + 6) * 2]; a1 += f * ws[(kb + 6) * 2 + 1];
        f = bf2f(v1.w); a0 += f * ws[(kb + 7) * 2]; a1 += f * ws[(kb + 7) * 2 + 1];
    }
    out[(size_t)i * 2 + 0] = a0;
    out[(size_t)i * 2 + 1] = a1;
}

extern "C" void kernel_launch(void* const* d_in, const int* in_sizes, int n_in,
                              void* d_out, int out_size, void* d_ws, size_t ws_size,
                              hipStream_t stream)
{
    const float* x     = (const float*)d_in[0];
    const float* W1l   = (const float*)d_in[1];
    const float* b1    = (const float*)d_in[2];
    const float* W1r   = (const float*)d_in[3];
    const float* W2l   = (const float*)d_in[4];
    const float* b2    = (const float*)d_in[5];
    const float* W2r   = (const float*)d_in[6];
    const float* gam   = (const float*)d_in[7];
    const float* bet   = (const float*)d_in[8];
    const float* bmean = (const float*)d_in[9];
    const float* bvar  = (const float*)d_in[10];
    const float* l1W   = (const float*)d_in[11];
    const float* l1b   = (const float*)d_in[12];
    const float* l2W   = (const float*)d_in[13];
    const float* l2b   = (const float*)d_in[14];
    const float* l3W   = (const float*)d_in[15];
    const float* l3b   = (const float*)d_in[16];
    const int*   ei    = (const int*)d_in[17];
    const int* src = ei, * dst = ei + NE;

    char* ws = (char*)d_ws;
    // liveness-overlaid workspace layout
    u16*   y1l  = (u16*)(ws + 0);            // [<=20224][1680] bf16 (dead after agg_bn)
    u16*   y1r  = (u16*)(ws + 68000000);     // [NN][1680] bf16 (dead after agg_bn)
    u16*   y2   = (u16*)(ws + 0);            // [NN][1280] bf16 (GEMM2 out; dead after agg_h2)
    u16*   o1   = (u16*)(ws + 0);            // [NN][320]  bf16
    u16*   o2   = (u16*)(ws + 16000000);     // [NN][160]  bf16
    u16*   xbf  = (u16*)(ws + 136000000);    // [NN][5120] bf16 (dead after gemm1f)
    u16*   hbuf = (u16*)(ws + 136000000);    // [NN][1792] bf16 (dead after GEMM2)
    u16*   h2   = (u16*)(ws + 136000000);    // [NN][640]  bf16
    u16*   w1T  = (u16*)(ws + 341000000);    // [3360][5120] bf16 (dead after gemm1f)
    u16*   w2T  = (u16*)(ws + 341000000);    // [1280][1792] bf16
    u16*   l1T  = (u16*)(ws + 346000000);    // [320][640] bf16
    u16*   l2T  = (u16*)(ws + 347000000);    // [160][320] bf16
    // CSR + compaction (persistent, after w1T's 375.41M end)
    int*   deg   = (int*)(ws + 375500000);   // [NN]
    int*   off   = (int*)(ws + 375584000);   // [NN+1]
    int*   cur   = (int*)(ws + 375668000);   // [NN]
    int*   cmark = (int*)(ws + 375752000);   // [NN] -> becomes cidx
    int*   clist = (int*)(ws + 375836000);   // [NN]
    int*   esrc  = (int*)(ws + 375920000);   // [NE]
    int*   nsrcp = (int*)(ws + 376050000);   // [1]

    // 0) CSR build + src compaction (independent of GEMMs)
    hipMemsetAsync(deg, 0, NN * sizeof(int), stream);
    hipMemsetAsync(cmark, 0, NN * sizeof(int), stream);
    deg_mark_k<<<(NE + 255) / 256, 256, 0, stream>>>(src, dst, deg, cmark, NE);
    scan2_k<<<1, 256, 0, stream>>>(deg, off, cur, cmark, clist, nsrcp);
    fill_k<<<(NE + 255) / 256, 256, 0, stream>>>(src, dst, cur, cmark, esrc, NE);

    // 1) x -> bf16 ; W1 -> [3360][5120] bf16 (transposed, concat [W1l|W1r])
    cvt_bf16<<<2048, 256, 0, stream>>>(x, xbf, NN * 5120 / 4);
    wtrans<<<dim3(160, 105), dim3(32, 8), 0, stream>>>(W1l, W1r, w1T, 5120, 5120, 3360, 1680);

    // 2) GEMM1 fused role-split: y1l (compacted src rows) + y1r (all rows)
    gemm1f<<<1106, 512, 0, stream>>>(xbf, w1T, y1l, y1r, clist, nsrcp);

    // 3) fused gather-mean + b1 + self + relu + BN -> hbuf (K-padded 1792)
    agg_bn_k<<<NN, 256, 0, stream>>>(y1l, y1r, off, esrc, b1, gam, bet, bmean, bvar, hbuf);

    // 4) W2 -> [1280][1792] bf16 (zero-padded K)
    wtrans<<<dim3(56, 40), dim3(32, 8), 0, stream>>>(W2l, W2r, w2T, 1680, 1792, 1280, 640);

    // 5) GEMM2 (8-phase 256^2): y2[NN][1280] = hbuf @ w2T^T
    gemm256<<<79 * 5, 512, 0, stream>>>(hbuf, w2T, y2, NN, 1280, 1792, 1792, 1792, 1280);

    // 6) fused gather-mean + b2 + self + relu -> h2
    agg_h2_k<<<NN, 192, 0, stream>>>(y2, off, esrc, clist, nsrcp, b2, h2);

    // 7) lin1/lin2 weights transposed
    wtrans<<<dim3(20, 10), dim3(32, 8), 0, stream>>>(l1W, l1W, l1T, 640, 640, 320, 320);
    wtrans<<<dim3(10, 5), dim3(32, 8), 0, stream>>>(l2W, l2W, l2T, 320, 320, 160, 160);

    // 8) GEMM3: o1 = relu(h2 @ l1T^T + l1b)   [NN][320]
    gemm_bt<1><<<157 * 3, 256, 0, stream>>>(h2, l1T, o1, l1b,
                                            NN, 320, 640, 640, 640, 320);

    // 9) GEMM4: o2 = relu(o1 @ l2T^T + l2b)  [NN][160]
    gemm_bt<1><<<157 * 2, 256, 0, stream>>>(o1, l2T, o2, l2b,
                                            NN, 160, 320, 320, 320, 160);

    // 10) lin3 -> out [NN][2] fp32
    lin3_k<<<(NN + 255) / 256, 256, 0, stream>>>(o2, l3W, l3b, (float*)d_out);
}

// Round 5
// 1048.104 us; speedup vs baseline: 1.1063x; 1.1063x over previous
//
#include <hip/hip_runtime.h>
#include <stdint.h>

#define NN 20000
#define NE 32000
#define BN_EPS 1e-5f

typedef __attribute__((ext_vector_type(8))) __bf16 bf16x8;
typedef __attribute__((ext_vector_type(4))) float f32x4;
typedef unsigned short u16;
typedef uint32_t u32;

__device__ __forceinline__ u16 f2bf(float f) {
    u32 u = __float_as_uint(f);
    u += 0x7FFFu + ((u >> 16) & 1u);
    return (u16)(u >> 16);
}
__device__ __forceinline__ float bf2f(u16 u) {
    return __uint_as_float(((u32)u) << 16);
}

__device__ __forceinline__ void gload_lds16(const void* g, void* l) {
    __builtin_amdgcn_global_load_lds(
        (const __attribute__((address_space(1))) void*)g,
        (__attribute__((address_space(3))) void*)(uintptr_t)l,
        16, 0, 0);
}

// ============ shared 8-phase machinery (T2+T3+T4+T5), 256x256, BK=64 ============
#define LDSRD(base, r, cb) (*(const bf16x8*)((const char*)(base) + (r)*128 + (cb)))

#define DS_A(apb, qm) do { \
  _Pragma("unroll") for (int m4_ = 0; m4_ < 4; ++m4_) { \
    int r_ = (qm)*128 + m4_*32 + wr16 + lrow; \
    aR[m4_][0] = LDSRD(apb, r_, cb0); \
    aR[m4_][1] = LDSRD(apb, r_, cb1); \
  } } while (0)

#define DS_B(bpb, qn) do { \
  _Pragma("unroll") for (int n2_ = 0; n2_ < 2; ++n2_) { \
    int n_ = (qn)*2 + n2_; \
    int r_ = n_*64 + wc16 + lrow; \
    bR[n_][0] = LDSRD(bpb, r_, cb0); \
    bR[n_][1] = LDSRD(bpb, r_, cb1); \
  } } while (0)

#define MM(qm, qn) do { \
  _Pragma("unroll") for (int m4_ = 0; m4_ < 4; ++m4_) \
  _Pragma("unroll") for (int n2_ = 0; n2_ < 2; ++n2_) { \
    int mi_ = (qm)*4 + m4_, ni_ = (qn)*2 + n2_; \
    acc[mi_][ni_] = __builtin_amdgcn_mfma_f32_16x16x32_bf16(aR[m4_][0], bR[ni_][0], acc[mi_][ni_], 0, 0, 0); \
    acc[mi_][ni_] = __builtin_amdgcn_mfma_f32_16x16x32_bf16(aR[m4_][1], bR[ni_][1], acc[mi_][ni_], 0, 0, 0); \
  } } while (0)

#define PHASE_TOP() do { __builtin_amdgcn_s_barrier(); \
  asm volatile("s_waitcnt lgkmcnt(0)" ::: "memory"); \
  __builtin_amdgcn_s_setprio(1); } while (0)
#define PHASE_END() do { __builtin_amdgcn_s_setprio(0); \
  __builtin_amdgcn_s_barrier(); } while (0)
#define PHASE_END_VM() do { __builtin_amdgcn_s_setprio(0); \
  asm volatile("s_waitcnt vmcnt(6)" ::: "memory"); \
  __builtin_amdgcn_s_barrier(); } while (0)

// K-loop body (identical schedule in both kernels); SA/SB are kernel-local macros
#define KLOOP_BODY(nit_) do { \
  for (int it = 0; it < (nit_); ++it) { \
    const int t1 = 2 * it + 1, t2 = 2 * it + 2, t3 = 2 * it + 3; \
    DS_A(&As[0][0][0], 0); DS_B(&Bs[0][0][0], 0); \
    SA(1, 1, t1); \
    PHASE_TOP(); MM(0, 0); PHASE_END(); \
    DS_B(&Bs[0][0][0], 1); \
    SA(0, 0, t2); \
    PHASE_TOP(); MM(0, 1); PHASE_END(); \
    DS_A(&As[0][0][0], 1); \
    SB(0, 0, t2); \
    PHASE_TOP(); MM(1, 1); PHASE_END(); \
    SB(0, 1, t2); \
    __builtin_amdgcn_s_barrier(); \
    __builtin_amdgcn_s_setprio(1); \
    MM(1, 0); \
    PHASE_END_VM(); \
    DS_A(&As[1][0][0], 0); DS_B(&Bs[1][0][0], 0); \
    SA(0, 1, t2); \
    PHASE_TOP(); MM(0, 0); PHASE_END(); \
    DS_B(&Bs[1][0][0], 1); \
    SA(1, 0, t3); \
    PHASE_TOP(); MM(0, 1); PHASE_END(); \
    DS_A(&As[1][0][0], 1); \
    SB(1, 0, t3); \
    PHASE_TOP(); MM(1, 1); PHASE_END(); \
    SB(1, 1, t3); \
    __builtin_amdgcn_s_barrier(); \
    __builtin_amdgcn_s_setprio(1); \
    MM(1, 0); \
    PHASE_END_VM(); \
  } } while (0)

// ================== GEMM1 fused (role-split L/R, A-row indirection) ==================
// role L: y1l[c][0:1680] = xbf[clist[c]] @ W1l^T  (c < nsrc, compacted src rows)
// role R: y1r[i][0:1680] = xbf[i]        @ W1r^T  (all NN rows)
// w1T = [3360][5120] bf16 rows = output cols; rows 0..1679 = W1l, 1680..3359 = W1r.
// Grid = 1106 (static upper bound); active blocks = nl + 553 at runtime.
// XCD balance: early-exit on RAW bid, then bijective swizzle over the RUNTIME
// active count so dead blocks spread across XCDs (round-4 lesson: swizzling
// over the static count concentrated all dead blocks on one XCD -> 5 rounds).
__global__ __launch_bounds__(512, 2) void gemm1f(
    const u16* __restrict__ xbf, const u16* __restrict__ w1T,
    u16* __restrict__ y1l, u16* __restrict__ y1r,
    const int* __restrict__ clist, const int* __restrict__ nsrcp)
{
    __shared__ __align__(16) u16 As[2][256][64];
    __shared__ __align__(16) u16 Bs[2][256][64];
    const int K = 5120, lda = 5120;
    const int Km64 = K - 64;

    const int nsrc = nsrcp[0];
    const int nmt_l = (nsrc + 255) >> 8;
    const int nl = nmt_l * 7;
    const int nwg = nl + 553;          // active blocks (994 for nsrc~16k)

    int bid = blockIdx.x;
    if (bid >= nwg) return;            // dead blocks: raw bid -> spread across XCDs
    int q8 = nwg >> 3, r8 = nwg & 7;
    int xcd = bid & 7, lid = bid >> 3;
    int wgid = (xcd < r8 ? xcd * (q8 + 1) : r8 * (q8 + 1) + (xcd - r8) * q8) + lid;

    int roleL = (wgid < nl);
    int local, nmt;
    if (roleL) { local = wgid; nmt = nmt_l; }
    else       { local = wgid - nl; nmt = 79; }
    // grouped raster GROUP_M=8, ntn=7
    int g = local / 56;
    int first = g << 3;
    int gsz = nmt - first; gsz = gsz < 8 ? gsz : 8;
    int rem = local - g * 56;
    int mt = first + rem % gsz;
    int nt = rem / gsz;

    const int m0 = mt << 8, n0 = nt << 8;
    const int tid = threadIdx.x;
    const int wid = tid >> 6, ln = tid & 63;
    const int wr = wid >> 2, wc = wid & 3;
    const int lrow = ln & 15, khi = ln >> 4;
    const int wr16 = wr << 4, wc16 = wc << 4;
    const int cb0 = (khi << 4) ^ ((lrow & 7) << 4);
    const int cb1 = cb0 ^ 64;
    const int row0 = tid >> 3;
    const int kel = ((tid & 7) ^ (row0 & 7)) << 3;
    const int dstoff = (tid & 448) << 4;

    // precomputed per-thread global row bases (i = ha*2 + {+0,+64})
    const u16* Bp = w1T + (roleL ? (size_t)0 : (size_t)1680 * 5120);
    const u16* aB[4];
    const u16* bB[4];
#pragma unroll
    for (int i = 0; i < 4; ++i) {
        int r = m0 + ((i >> 1) << 7) + ((i & 1) << 6) + row0;
        int ga;
        if (roleL) { int idx = r < nsrc ? r : nsrc - 1; ga = clist[idx]; }
        else       { ga = r < NN ? r : NN - 1; }
        aB[i] = xbf + (size_t)ga * lda + kel;
        int rb = n0 + ((i >> 1) << 7) + ((i & 1) << 6) + row0;
        rb = rb < 1680 ? rb : 1679;
        bB[i] = Bp + (size_t)rb * lda + kel;
    }

#define SA(b, ha, t) do { int ks_ = (t) * 64; if (ks_ > Km64) ks_ = Km64; \
  char* d_ = (char*)&As[b][(ha)*128][0] + dstoff; \
  gload_lds16(aB[(ha)*2] + ks_, d_); \
  gload_lds16(aB[(ha)*2 + 1] + ks_, d_ + 8192); } while (0)
#define SB(b, hb, t) do { int ks_ = (t) * 64; if (ks_ > Km64) ks_ = Km64; \
  char* d_ = (char*)&Bs[b][(hb)*128][0] + dstoff; \
  gload_lds16(bB[(hb)*2] + ks_, d_); \
  gload_lds16(bB[(hb)*2 + 1] + ks_, d_ + 8192); } while (0)

    f32x4 acc[8][4];
#pragma unroll
    for (int m = 0; m < 8; ++m)
#pragma unroll
        for (int n = 0; n < 4; ++n)
#pragma unroll
            for (int j = 0; j < 4; ++j) acc[m][n][j] = 0.f;
    bf16x8 aR[4][2], bR[4][2];

    SA(0, 0, 0); SB(0, 0, 0); SB(0, 1, 0); SA(0, 1, 0);
    SA(1, 0, 1); SB(1, 0, 1); SB(1, 1, 1);
    asm volatile("s_waitcnt vmcnt(6)" ::: "memory");
    __builtin_amdgcn_s_barrier();

    KLOOP_BODY(40);

#undef SA
#undef SB

    const int Meff = roleL ? nsrc : NN;
    u16* C = roleL ? y1l : y1r;
#pragma unroll
    for (int m = 0; m < 8; ++m) {
        int gr0 = m0 + m * 32 + wr16 + (khi << 2);
#pragma unroll
        for (int n = 0; n < 4; ++n) {
            int gc = n0 + n * 64 + wc16 + lrow;
            if (gc >= 1680) continue;
#pragma unroll
            for (int j = 0; j < 4; ++j) {
                int gr = gr0 + j;
                if (gr >= Meff) continue;
                C[(size_t)gr * 1680 + gc] = f2bf(acc[m][n][j]);
            }
        }
    }
}

// ================== generic 256x256 8-phase GEMM (GEMM2) ==================
__global__ __launch_bounds__(512, 2) void gemm256(
    const u16* __restrict__ A, const u16* __restrict__ B, u16* __restrict__ C,
    int M, int N, int K, int lda, int ldb, int ldc)
{
    __shared__ __align__(16) u16 As[2][256][64];
    __shared__ __align__(16) u16 Bs[2][256][64];

    const int nmt = (M + 255) >> 8;
    const int ntn = (N + 255) >> 8;
    const int nwg = nmt * ntn;

    int bid = blockIdx.x;
    int q8 = nwg >> 3, r8 = nwg & 7;
    int xcd = bid & 7, lid = bid >> 3;
    int wgid = (xcd < r8 ? xcd * (q8 + 1) : r8 * (q8 + 1) + (xcd - r8) * q8) + lid;
    int per = ntn << 3;
    int g = wgid / per;
    int first = g << 3;
    int gsz = nmt - first; gsz = gsz < 8 ? gsz : 8;
    int rem = wgid - g * per;
    int mt = first + rem % gsz;
    int nt = rem / gsz;

    const int m0 = mt << 8, n0 = nt << 8;
    const int tid = threadIdx.x;
    const int wid = tid >> 6, ln = tid & 63;
    const int wr = wid >> 2, wc = wid & 3;
    const int lrow = ln & 15, khi = ln >> 4;
    const int wr16 = wr << 4, wc16 = wc << 4;
    const int cb0 = (khi << 4) ^ ((lrow & 7) << 4);
    const int cb1 = cb0 ^ 64;
    const int row0 = tid >> 3;
    const int kel = ((tid & 7) ^ (row0 & 7)) << 3;
    const int dstoff = (tid & 448) << 4;
    const int Km64 = K - 64;

#define SA(b, ha, t) do { int ks_ = (t) * 64; if (ks_ > Km64) ks_ = Km64; \
  int ra_ = m0 + (ha)*128 + row0;      ra_ = ra_ < M ? ra_ : M - 1; \
  int rb_ = m0 + (ha)*128 + row0 + 64; rb_ = rb_ < M ? rb_ : M - 1; \
  char* d_ = (char*)&As[b][(ha)*128][0] + dstoff; \
  gload_lds16(A + (size_t)ra_ * lda + ks_ + kel, d_); \
  gload_lds16(A + (size_t)rb_ * lda + ks_ + kel, d_ + 8192); } while (0)
#define SB(b, hb, t) do { int ks_ = (t) * 64; if (ks_ > Km64) ks_ = Km64; \
  int ra_ = n0 + (hb)*128 + row0;      ra_ = ra_ < N ? ra_ : N - 1; \
  int rb_ = n0 + (hb)*128 + row0 + 64; rb_ = rb_ < N ? rb_ : N - 1; \
  char* d_ = (char*)&Bs[b][(hb)*128][0] + dstoff; \
  gload_lds16(B + (size_t)ra_ * ldb + ks_ + kel, d_); \
  gload_lds16(B + (size_t)rb_ * ldb + ks_ + kel, d_ + 8192); } while (0)

    f32x4 acc[8][4];
#pragma unroll
    for (int m = 0; m < 8; ++m)
#pragma unroll
        for (int n = 0; n < 4; ++n)
#pragma unroll
            for (int j = 0; j < 4; ++j) acc[m][n][j] = 0.f;
    bf16x8 aR[4][2], bR[4][2];

    SA(0, 0, 0); SB(0, 0, 0); SB(0, 1, 0); SA(0, 1, 0);
    SA(1, 0, 1); SB(1, 0, 1); SB(1, 1, 1);
    asm volatile("s_waitcnt vmcnt(6)" ::: "memory");
    __builtin_amdgcn_s_barrier();

    const int nit = K >> 7;
    KLOOP_BODY(nit);

#undef SA
#undef SB

#pragma unroll
    for (int m = 0; m < 8; ++m) {
        int gr0 = m0 + m * 32 + wr16 + (khi << 2);
#pragma unroll
        for (int n = 0; n < 4; ++n) {
            int gc = n0 + n * 64 + wc16 + lrow;
            if (gc >= N) continue;
#pragma unroll
            for (int j = 0; j < 4; ++j) {
                int gr = gr0 + j;
                if (gr >= M) continue;
                C[(size_t)gr * ldc + gc] = f2bf(acc[m][n][j]);
            }
        }
    }
}

// ================== 128x128 GEMM (small layers) ==================
template <int EPI>
__global__ __launch_bounds__(256, 2) void gemm_bt(
    const u16* __restrict__ A, const u16* __restrict__ B, u16* __restrict__ C,
    const float* __restrict__ bias, int M, int N, int K, int lda, int ldb, int ldc)
{
    __shared__ __align__(16) u16 As[128][64];
    __shared__ __align__(16) u16 Bs[128][64];

    const int nmt = (M + 127) >> 7;
    const int ntn = (N + 127) >> 7;
    int bid = blockIdx.x;
    int per_grp = 16 * ntn;
    int g = bid / per_grp;
    int first = g * 16;
    int gsz = min(16, nmt - first);
    int rem = bid - g * per_grp;
    int mt = first + rem % gsz;
    int nt = rem / gsz;

    const int m0 = mt << 7, n0 = nt << 7;
    const int tid = threadIdx.x;
    const int wv = tid >> 6, ln = tid & 63;
    const int wr = wv >> 1, wc = wv & 1;

    f32x4 acc[4][4];
#pragma unroll
    for (int m = 0; m < 4; ++m)
#pragma unroll
        for (int n = 0; n < 4; ++n)
#pragma unroll
            for (int j = 0; j < 4; ++j) acc[m][n][j] = 0.f;

    const int lrow = ln & 15;
    const int koff = (ln >> 4) << 3;

    for (int k0 = 0; k0 < K; k0 += 64) {
#pragma unroll
        for (int r = 0; r < 4; ++r) {
            int c = r * 256 + wv * 64 + ln;
            int row = c >> 3;
            int kc = (c & 7) << 3;
            int ga = m0 + row; ga = ga < M ? ga : M - 1;
            gload_lds16(A + (size_t)ga * lda + (k0 + kc),
                        (char*)&As[0][0] + (size_t)(r * 256 + wv * 64) * 16);
            int gb = n0 + row; gb = gb < N ? gb : N - 1;
            gload_lds16(B + (size_t)gb * ldb + (k0 + kc),
                        (char*)&Bs[0][0] + (size_t)(r * 256 + wv * 64) * 16);
        }
        __syncthreads();
#pragma unroll
        for (int kk = 0; kk < 2; ++kk) {
            bf16x8 af[4], bfr[4];
            const int krd = (kk << 5) + koff;
#pragma unroll
            for (int m = 0; m < 4; ++m)
                af[m] = *(const bf16x8*)&As[(wr << 6) + (m << 4) + lrow][krd];
#pragma unroll
            for (int n = 0; n < 4; ++n)
                bfr[n] = *(const bf16x8*)&Bs[(wc << 6) + (n << 4) + lrow][krd];
#pragma unroll
            for (int m = 0; m < 4; ++m)
#pragma unroll
                for (int n = 0; n < 4; ++n)
                    acc[m][n] = __builtin_amdgcn_mfma_f32_16x16x32_bf16(
                        af[m], bfr[n], acc[m][n], 0, 0, 0);
        }
        __syncthreads();
    }

    const int colb = ln & 15;
    const int rowb = (ln >> 4) << 2;
#pragma unroll
    for (int m = 0; m < 4; ++m) {
        int gr0 = m0 + (wr << 6) + (m << 4) + rowb;
#pragma unroll
        for (int n = 0; n < 4; ++n) {
            int gc = n0 + (wc << 6) + (n << 4) + colb;
            if (gc >= N) continue;
            float bv = (EPI == 1) ? bias[gc] : 0.f;
#pragma unroll
            for (int j = 0; j < 4; ++j) {
                int gr = gr0 + j;
                if (gr >= M) continue;
                float v = acc[m][n][j];
                if (EPI == 1) { v += bv; v = v > 0.f ? v : 0.f; }
                C[(size_t)gr * ldc + gc] = f2bf(v);
            }
        }
    }
}

// ---------------- fp32 -> bf16 convert (grid-stride)
__global__ void cvt_bf16(const float* __restrict__ in, u16* __restrict__ out, int n4)
{
    for (int i = blockIdx.x * 256 + threadIdx.x; i < n4; i += gridDim.x * 256) {
        float4 v = ((const float4*)in)[i];
        ushort4 o;
        o.x = f2bf(v.x); o.y = f2bf(v.y); o.z = f2bf(v.z); o.w = f2bf(v.w);
        ((ushort4*)out)[i] = o;
    }
}

// ---------------- weight transpose+convert: out[n][k](bf16,ld=Kpad) = src[k][n](f32)
__global__ void wtrans(const float* __restrict__ s0, const float* __restrict__ s1,
                       u16* __restrict__ out, int Kin, int Kpad, int N, int nsplit)
{
    __shared__ float t[32][33];
    int k0 = blockIdx.x << 5, n0 = blockIdx.y << 5;
    int tx = threadIdx.x, ty = threadIdx.y;
#pragma unroll
    for (int i = 0; i < 4; ++i) {
        int k = k0 + ty + (i << 3);
        int n = n0 + tx;
        float v = 0.f;
        if (k < Kin && n < N)
            v = (n < nsplit) ? s0[(size_t)k * nsplit + n]
                             : s1[(size_t)k * (N - nsplit) + (n - nsplit)];
        t[ty + (i << 3)][tx] = v;
    }
    __syncthreads();
#pragma unroll
    for (int i = 0; i < 4; ++i) {
        int n = n0 + ty + (i << 3);
        int k = k0 + tx;
        if (n < N && k < Kpad)
            out[(size_t)n * Kpad + k] = f2bf(t[tx][ty + (i << 3)]);
    }
}

// ================== CSR build + src compaction ==================
__global__ void deg_mark_k(const int* __restrict__ src, const int* __restrict__ dst,
                           int* __restrict__ deg, int* __restrict__ cmark, int ne)
{
    int e = blockIdx.x * 256 + threadIdx.x;
    if (e < ne) {
        atomicAdd(&deg[dst[e]], 1);
        cmark[src[e]] = 1;
    }
}

// single block: prefix-scan deg -> off/cur, prefix-scan cmark -> cidx (in place) + clist
__global__ __launch_bounds__(256) void scan2_k(
    const int* __restrict__ deg, int* __restrict__ off, int* __restrict__ cur,
    int* __restrict__ cmark, int* __restrict__ clist, int* __restrict__ nsrcp)
{
    __shared__ int part[256];
    int t = threadIdx.x;
    int st = t * 79;
    // scan 1: deg
    int s = 0;
    for (int j = 0; j < 79; ++j) { int i = st + j; if (i < NN) s += deg[i]; }
    part[t] = s;
    __syncthreads();
    for (int d = 1; d < 256; d <<= 1) {
        int v = (t >= d) ? part[t - d] : 0;
        __syncthreads(); part[t] += v; __syncthreads();
    }
    int run = part[t] - s;
    for (int j = 0; j < 79; ++j) {
        int i = st + j;
        if (i < NN) { off[i] = run; cur[i] = run; run += deg[i]; }
    }
    if (t == 255) off[NN] = NE;
    __syncthreads();
    // scan 2: cmark -> cidx (in place), emit clist
    int s2 = 0;
    for (int j = 0; j < 79; ++j) { int i = st + j; if (i < NN) s2 += cmark[i]; }
    part[t] = s2;
    __syncthreads();
    for (int d = 1; d < 256; d <<= 1) {
        int v = (t >= d) ? part[t - d] : 0;
        __syncthreads(); part[t] += v; __syncthreads();
    }
    int run2 = part[t] - s2;
    for (int j = 0; j < 79; ++j) {
        int i = st + j;
        if (i < NN) {
            int m = cmark[i];
            if (m) clist[run2] = i;
            cmark[i] = run2;       // cmark becomes cidx
            run2 += m;
        }
    }
    if (t == 255) nsrcp[0] = part[255];
}

__global__ void fill_k(const int* __restrict__ src, const int* __restrict__ dst,
                       int* __restrict__ cur, const int* __restrict__ cidx,
                       int* __restrict__ esrc, int ne)
{
    int e = blockIdx.x * 256 + threadIdx.x;
    if (e < ne) {
        int p = atomicAdd(&cur[dst[e]], 1);
        esrc[p] = cidx[src[e]];     // compact id
    }
}

// ================== fused gather-mean + epilogue, layer 1 ==================
__device__ __forceinline__ void bn_emit(
    int b, int c, float sx, float sy, float sz, float sw, float inv,
    const u16* __restrict__ y1r, const float* __restrict__ b1,
    const float* __restrict__ gam, const float* __restrict__ bet,
    const float* __restrict__ mn, const float* __restrict__ vr, u16* __restrict__ h)
{
    int col = c << 2;
    ushort4 yr = *(const ushort4*)&y1r[(size_t)b * 1680 + col];
    float4 bb = *(const float4*)&b1[col];
    float4 g4 = *(const float4*)&gam[col];
    float4 be = *(const float4*)&bet[col];
    float4 m4 = *(const float4*)&mn[col];
    float4 v4 = *(const float4*)&vr[col];
    float t0 = fmaxf(sx * inv + bb.x + bf2f(yr.x), 0.f);
    float t1 = fmaxf(sy * inv + bb.y + bf2f(yr.y), 0.f);
    float t2 = fmaxf(sz * inv + bb.z + bf2f(yr.z), 0.f);
    float t3 = fmaxf(sw * inv + bb.w + bf2f(yr.w), 0.f);
    t0 = (t0 - m4.x) * rsqrtf(v4.x + BN_EPS) * g4.x + be.x;
    t1 = (t1 - m4.y) * rsqrtf(v4.y + BN_EPS) * g4.y + be.y;
    t2 = (t2 - m4.z) * rsqrtf(v4.z + BN_EPS) * g4.z + be.z;
    t3 = (t3 - m4.w) * rsqrtf(v4.w + BN_EPS) * g4.w + be.w;
    ushort4 o;
    o.x = f2bf(t0); o.y = f2bf(t1); o.z = f2bf(t2); o.w = f2bf(t3);
    *(ushort4*)&h[(size_t)b * 1792 + col] = o;
}

__global__ __launch_bounds__(256) void agg_bn_k(
    const u16* __restrict__ y1l, const u16* __restrict__ y1r,
    const int* __restrict__ off, const int* __restrict__ esrc,
    const float* __restrict__ b1, const float* __restrict__ gam, const float* __restrict__ bet,
    const float* __restrict__ mn, const float* __restrict__ vr, u16* __restrict__ h)
{
    int b = blockIdx.x, t = threadIdx.x;
    int o0 = off[b], o1 = off[b + 1];
    int deg = o1 - o0;
    const int c0 = t, c1 = t + 256;   // ushort4 chunks; 420 data chunks, 448 total (pad)
    float s0x = 0.f, s0y = 0.f, s0z = 0.f, s0w = 0.f;
    float s1x = 0.f, s1y = 0.f, s1z = 0.f, s1w = 0.f;
    for (int j = o0; j < o1; ++j) {
        int s = esrc[j];            // compact id into y1l
        const u16* row = y1l + (size_t)s * 1680;
        ushort4 v = *(const ushort4*)&row[c0 << 2];
        s0x += bf2f(v.x); s0y += bf2f(v.y); s0z += bf2f(v.z); s0w += bf2f(v.w);
        if (t < 164) {
            ushort4 w = *(const ushort4*)&row[c1 << 2];
            s1x += bf2f(w.x); s1y += bf2f(w.y); s1z += bf2f(w.z); s1w += bf2f(w.w);
        }
    }
    float inv = 1.f / (deg > 1 ? (float)deg : 1.f);
    bn_emit(b, c0, s0x, s0y, s0z, s0w, inv, y1r, b1, gam, bet, mn, vr, h);
    if (t < 164) {
        bn_emit(b, c1, s1x, s1y, s1z, s1w, inv, y1r, b1, gam, bet, mn, vr, h);
    } else if (t < 192) {
        ushort4 z; z.x = 0; z.y = 0; z.z = 0; z.w = 0;
        *(ushort4*)&h[(size_t)b * 1792 + (c1 << 2)] = z;   // pad chunks 420..447
    }
}

// ================== fused gather-mean + epilogue, layer 2 ==================
__global__ __launch_bounds__(192) void agg_h2_k(
    const u16* __restrict__ y2, const int* __restrict__ off, const int* __restrict__ esrc,
    const int* __restrict__ clist, const int* __restrict__ nsrcp,
    const float* __restrict__ b2, u16* __restrict__ h2)
{
    int b = blockIdx.x, t = threadIdx.x;
    if (t >= 160) return;
    int o0 = off[b], o1 = off[b + 1];
    int deg = o1 - o0;
    float sx = 0.f, sy = 0.f, sz = 0.f, sw = 0.f;
    for (int j = o0; j < o1; ++j) {
        int s = clist[esrc[j]];     // original node id
        ushort4 v = *(const ushort4*)&y2[(size_t)s * 1280 + (t << 2)];
        sx += bf2f(v.x); sy += bf2f(v.y); sz += bf2f(v.z); sw += bf2f(v.w);
    }
    float inv = 1.f / (deg > 1 ? (float)deg : 1.f);
    int col = t << 2;
    ushort4 yr = *(const ushort4*)&y2[(size_t)b * 1280 + 640 + col];
    float4 bb = *(const float4*)&b2[col];
    ushort4 o;
    o.x = f2bf(fmaxf(sx * inv + bb.x + bf2f(yr.x), 0.f));
    o.y = f2bf(fmaxf(sy * inv + bb.y + bf2f(yr.y), 0.f));
    o.z = f2bf(fmaxf(sz * inv + bb.z + bf2f(yr.z), 0.f));
    o.w = f2bf(fmaxf(sw * inv + bb.w + bf2f(yr.w), 0.f));
    *(ushort4*)&h2[(size_t)b * 640 + col] = o;
}

// ---------------- final lin3
__global__ void lin3_k(const u16* __restrict__ o2, const float* __restrict__ W,
                       const float* __restrict__ b, float* __restrict__ out)
{
    __shared__ float ws[320];
    for (int j = threadIdx.x; j < 320; j += 256) ws[j] = W[j];
    __syncthreads();
    int i = blockIdx.x * 256 + threadIdx.x;
    if (i >= NN) return;
    float a0 = b[0], a1 = b[1];
    const u16* row = o2 + (size_t)i * 160;
#pragma unroll
    for (int k8 = 0; k8 < 20; ++k8) {
        ushort4 v0 = *(const ushort4*)&row[k8 * 8];
        ushort4 v1 = *(const ushort4*)&row[k8 * 8 + 4];
        int kb = k8 * 8;
        float f;
        f = bf2f(v0.x); a0 += f * ws[(kb + 0) * 2]; a1 += f * ws[(kb + 0) * 2 + 1];
        f = bf2f(v0.y); a0 += f * ws[(kb + 1) * 2]; a1 += f * ws[(kb + 1) * 2 + 1];
        f = bf2f(v0.z); a0 += f * ws[(kb + 2) * 2]; a1 += f * ws[(kb + 2) * 2 + 1];
        f = bf2f(v0.w); a0 += f * ws[(kb + 3) * 2]; a1 += f * ws[(kb + 3) * 2 + 1];
        f = bf2f(v1.x); a0 += f * ws[(kb + 4) * 2]; a1 += f * ws[(kb + 4) * 2 + 1];
        f = bf2f(v1.y); a0 += f * ws[(kb + 5) * 2]; a1 += f * ws[(kb + 5) * 2 + 1];
        f = bf2f(v1.z); a0 += f * ws[(kb + 6) * 2]; a1 += f * ws[(kb + 6) * 2 + 1];
        f = bf2f(v1.w); a0 += f * ws[(kb + 7) * 2]; a1 += f * ws[(kb + 7) * 2 + 1];
    }
    out[(size_t)i * 2 + 0] = a0;
    out[(size_t)i * 2 + 1] = a1;
}

extern "C" void kernel_launch(void* const* d_in, const int* in_sizes, int n_in,
                              void* d_out, int out_size, void* d_ws, size_t ws_size,
                              hipStream_t stream)
{
    const float* x     = (const float*)d_in[0];
    const float* W1l   = (const float*)d_in[1];
    const float* b1    = (const float*)d_in[2];
    const float* W1r   = (const float*)d_in[3];
    const float* W2l   = (const float*)d_in[4];
    const float* b2    = (const float*)d_in[5];
    const float* W2r   = (const float*)d_in[6];
    const float* gam   = (const float*)d_in[7];
    const float* bet   = (const float*)d_in[8];
    const float* bmean = (const float*)d_in[9];
    const float* bvar  = (const float*)d_in[10];
    const float* l1W   = (const float*)d_in[11];
    const float* l1b   = (const float*)d_in[12];
    const float* l2W   = (const float*)d_in[13];
    const float* l2b   = (const float*)d_in[14];
    const float* l3W   = (const float*)d_in[15];
    const float* l3b   = (const float*)d_in[16];
    const int*   ei    = (const int*)d_in[17];
    const int* src = ei, * dst = ei + NE;

    char* ws = (char*)d_ws;
    // liveness-overlaid workspace layout
    u16*   y1l  = (u16*)(ws + 0);            // [<=20224][1680] bf16 (dead after agg_bn)
    u16*   y1r  = (u16*)(ws + 68000000);     // [NN][1680] bf16 (dead after agg_bn)
    u16*   y2   = (u16*)(ws + 0);            // [NN][1280] bf16 (GEMM2 out; dead after agg_h2)
    u16*   o1   = (u16*)(ws + 0);            // [NN][320]  bf16
    u16*   o2   = (u16*)(ws + 16000000);     // [NN][160]  bf16
    u16*   xbf  = (u16*)(ws + 136000000);    // [NN][5120] bf16 (dead after gemm1f)
    u16*   hbuf = (u16*)(ws + 136000000);    // [NN][1792] bf16 (dead after GEMM2)
    u16*   h2   = (u16*)(ws + 136000000);    // [NN][640]  bf16
    u16*   w1T  = (u16*)(ws + 341000000);    // [3360][5120] bf16 (dead after gemm1f)
    u16*   w2T  = (u16*)(ws + 341000000);    // [1280][1792] bf16
    u16*   l1T  = (u16*)(ws + 346000000);    // [320][640] bf16
    u16*   l2T  = (u16*)(ws + 347000000);    // [160][320] bf16
    // CSR + compaction (persistent, after w1T's 375.41M end)
    int*   deg   = (int*)(ws + 375500000);   // [NN]
    int*   off   = (int*)(ws + 375584000);   // [NN+1]
    int*   cur   = (int*)(ws + 375668000);   // [NN]
    int*   cmark = (int*)(ws + 375752000);   // [NN] -> becomes cidx
    int*   clist = (int*)(ws + 375836000);   // [NN]
    int*   esrc  = (int*)(ws + 375920000);   // [NE]
    int*   nsrcp = (int*)(ws + 376050000);   // [1]

    // 0) CSR build + src compaction (independent of GEMMs)
    hipMemsetAsync(deg, 0, NN * sizeof(int), stream);
    hipMemsetAsync(cmark, 0, NN * sizeof(int), stream);
    deg_mark_k<<<(NE + 255) / 256, 256, 0, stream>>>(src, dst, deg, cmark, NE);
    scan2_k<<<1, 256, 0, stream>>>(deg, off, cur, cmark, clist, nsrcp);
    fill_k<<<(NE + 255) / 256, 256, 0, stream>>>(src, dst, cur, cmark, esrc, NE);

    // 1) x -> bf16 ; W1 -> [3360][5120] bf16 (transposed, concat [W1l|W1r])
    cvt_bf16<<<2048, 256, 0, stream>>>(x, xbf, NN * 5120 / 4);
    wtrans<<<dim3(160, 105), dim3(32, 8), 0, stream>>>(W1l, W1r, w1T, 5120, 5120, 3360, 1680);

    // 2) GEMM1 fused role-split: y1l (compacted src rows) + y1r (all rows)
    gemm1f<<<1106, 512, 0, stream>>>(xbf, w1T, y1l, y1r, clist, nsrcp);

    // 3) fused gather-mean + b1 + self + relu + BN -> hbuf (K-padded 1792)
    agg_bn_k<<<NN, 256, 0, stream>>>(y1l, y1r, off, esrc, b1, gam, bet, bmean, bvar, hbuf);

    // 4) W2 -> [1280][1792] bf16 (zero-padded K)
    wtrans<<<dim3(56, 40), dim3(32, 8), 0, stream>>>(W2l, W2r, w2T, 1680, 1792, 1280, 640);

    // 5) GEMM2 (8-phase 256^2): y2[NN][1280] = hbuf @ w2T^T
    gemm256<<<79 * 5, 512, 0, stream>>>(hbuf, w2T, y2, NN, 1280, 1792, 1792, 1792, 1280);

    // 6) fused gather-mean + b2 + self + relu -> h2
    agg_h2_k<<<NN, 192, 0, stream>>>(y2, off, esrc, clist, nsrcp, b2, h2);

    // 7) lin1/lin2 weights transposed
    wtrans<<<dim3(20, 10), dim3(32, 8), 0, stream>>>(l1W, l1W, l1T, 640, 640, 320, 320);
    wtrans<<<dim3(10, 5), dim3(32, 8), 0, stream>>>(l2W, l2W, l2T, 320, 320, 160, 160);

    // 8) GEMM3: o1 = relu(h2 @ l1T^T + l1b)   [NN][320]
    gemm_bt<1><<<157 * 3, 256, 0, stream>>>(h2, l1T, o1, l1b,
                                            NN, 320, 640, 640, 640, 320);

    // 9) GEMM4: o2 = relu(o1 @ l2T^T + l2b)  [NN][160]
    gemm_bt<1><<<157 * 2, 256, 0, stream>>>(o1, l2T, o2, l2b,
                                            NN, 160, 320, 320, 320, 160);

    // 10) lin3 -> out [NN][2] fp32
    lin3_k<<<(NN + 255) / 256, 256, 0, stream>>>(o2, l3W, l3b, (float*)d_out);
}